// Round 8
// baseline (134.902 us; speedup 1.0000x reference)
//
#include <hip/hip_runtime.h>
#include <stdint.h>
#include <stddef.h>

// out[b, p*768+e] = sum_d x[b,d]*W[p,d]*GE[d,e] + bias[p]
// == per-b GEMM: OUT_b(256x768) = (diag(x_b) W)(256x2048) @ GT^T + bias
//
// R13 vs R12: same proven geometry (4b x 128p x 96e, 8 waves 4wm x 2wn,
// batch-share x4, grid 256 = 1/CU, reads:MFMA 0.375) but the K-loop is an
// exact port of the m201 8-phase discipline (the only structure measured
// breaking the pipe-sum law, 62% MfmaUtil): 4 phases/tile x 12 MFMA, each
// {ds-reads || exactly 1 global_load_lds -> bar -> lgkm0+sched_barrier ->
// setprio(1) -> pk_muls + MFMA -> setprio(0) -> bar}; UNIFORM vmcnt ledger
// (every wave issues exactly 4 gloads/tile: A0@P0,A1@P1,B0@P2,B1@P3; B LDS
// padded to 128 rows w/ clamped source rows so both B calls are full-width);
// ONE counted gate vmcnt(4)/tile at P3 (never 0 until tail); DEPTH-2
// prefetch via 3 LDS buffers (tile t+2 staged while t is read - no
// write-into-read-buffer race). X whole-row in LDS outside the ledger
// (broadcast b128 reads, ~free per m136 same-address rule).
// LDS 112KB: A[3][128][64] 48K | B[3][128][64] 48K | X[4][2048] 16K.
//
// Workspace: xb 64x2048 f16 (262144 B) | Wb 256x2048 f16 (1048576 B) |
// GT 768x2048 f16 (3145728 B) = 4,456,448 B total.

#define F_GENES 2000
#define KPAD    2048
#define P_PATH  256
#define EMB     768
#define BATCH   64
#define NT      32        // K tiles of BK=64

typedef _Float16 f16x8 __attribute__((ext_vector_type(8)));
typedef float    f32x4 __attribute__((ext_vector_type(4)));

__device__ __forceinline__ unsigned short f2h(float f) {
    union { _Float16 h; unsigned short s; } v; v.h = (_Float16)f; return v.s;
}

__device__ __forceinline__ void gload16(const void* g, void* l) {
    __builtin_amdgcn_global_load_lds((const __attribute__((address_space(1))) void*)g,
                                     (__attribute__((address_space(3))) void*)l,
                                     16, 0, 0);
}

// K1: pack x (64 rows) + W (256 rows) fp32 -> fp16, K-padded to 2048 w/ zeros.
__global__ void pack_xw_kernel(const float* __restrict__ x,
                               const float* __restrict__ w,
                               unsigned short* __restrict__ xb,
                               unsigned short* __restrict__ wb) {
    int gid = blockIdx.x * 256 + threadIdx.x;
    int row = gid >> 8;
    int s   = gid & 255;
    int d0  = s * 8;
    const float* src;
    unsigned short* dst;
    if (row < BATCH) { src = x + (size_t)row * F_GENES;           dst = xb + (size_t)row * KPAD; }
    else             { src = w + (size_t)(row - BATCH) * F_GENES; dst = wb + (size_t)(row - BATCH) * KPAD; }
    uint4 ov = make_uint4(0u, 0u, 0u, 0u);
    if (s < 250) {
        float4 v0 = *(const float4*)(src + d0);
        float4 v1 = *(const float4*)(src + d0 + 4);
        unsigned short* os = (unsigned short*)&ov;
        os[0] = f2h(v0.x); os[1] = f2h(v0.y); os[2] = f2h(v0.z); os[3] = f2h(v0.w);
        os[4] = f2h(v1.x); os[5] = f2h(v1.y); os[6] = f2h(v1.z); os[7] = f2h(v1.w);
    }
    *(uint4*)(dst + d0) = ov;
}

// K2: GT[n,k] = f16(GE[k,n]), k-padded to 2048.
__global__ void transpose_ge_kernel(const float* __restrict__ ge,
                                    unsigned short* __restrict__ GT) {
    __shared__ unsigned short tile[64][40];
    int kt = blockIdx.x & 63;
    int nt = blockIdx.x >> 6;
    int k0 = kt * 32, n0 = nt * 64;
    int t  = threadIdx.x;
    int kr = t >> 4;
    int nc = (t & 15) * 4;
#pragma unroll
    for (int p = 0; p < 2; ++p) {
        int k = k0 + p * 16 + kr;
        float4 v = make_float4(0.f, 0.f, 0.f, 0.f);
        if (k < F_GENES) v = *(const float4*)(ge + (size_t)k * EMB + n0 + nc);
        int kk = p * 16 + kr;
        tile[nc + 0][kk] = f2h(v.x);
        tile[nc + 1][kk] = f2h(v.y);
        tile[nc + 2][kk] = f2h(v.z);
        tile[nc + 3][kk] = f2h(v.w);
    }
    __syncthreads();
    int n  = t >> 2;
    int kc = (t & 3) * 8;
    uint4 o;
    unsigned short* os = (unsigned short*)&o;
#pragma unroll
    for (int j = 0; j < 8; ++j) os[j] = tile[n][kc + j];
    *(uint4*)(GT + (size_t)(n0 + n) * KPAD + k0 + kc) = o;
}

// ---- GEMM: 4-batch-shared 128x96 tile, 8 waves, m201 4-phase pipeline ----
// LDS (f16 units): A [3 buf][128 row][64 k] @0      (24576 f16, 48 KB)
//                  B [3 buf][128 row][64 k] @24576  (24576 f16, 48 KB; rows 96-127 pad)
//                  X [4 b][2048 k]          @49152  ( 8192 f16, 16 KB)
#define A_OFF 0
#define B_OFF 24576
#define X_OFF 49152

#define SBAR() __builtin_amdgcn_sched_barrier(0)
#define BAR()  do { SBAR(); __builtin_amdgcn_s_barrier(); SBAR(); } while (0)
#define LGKM0() do { asm volatile("s_waitcnt lgkmcnt(0)" ::: "memory"); SBAR(); } while (0)

__global__ __launch_bounds__(512, 2)
void gemm_kernel(const _Float16* __restrict__ xb, const _Float16* __restrict__ Wb,
                 const _Float16* __restrict__ GT, const float* __restrict__ bias,
                 float* __restrict__ out) {
    __shared__ __align__(16) _Float16 smem[57344];   // 112 KB

    const int tid  = threadIdx.x;
    const int wv   = tid >> 6;        // wave 0..7
    const int l    = tid & 63;
    const int quad = l >> 4;
    const int ln   = l & 15;
    const int wm   = wv >> 1;         // 0..3 (32 p-rows each)
    const int wn   = wv & 1;          // 0..1 (48 cols each)

    const int ct = blockIdx.x & 7;          // 768 / 96
    const int ph = (blockIdx.x >> 3) & 1;   // pathway half (128 rows of W)
    const int bq = blockIdx.x >> 4;         // batch quad 0..15
    const int b0 = 4 * bq;

    // staging maps: row = call*64 + (tid>>3), chunk slot = tid&7,
    // source chunk = slot ^ (row&7) = slot ^ ((tid>>3)&7). LDS dest linear tid*8.
    const int srow = tid >> 3;
    const int schk = (tid & 7) ^ (srow & 7);
    const _Float16* Ag  = Wb + (size_t)(ph * 128 + srow) * KPAD + schk * 8;
    // B rows: call0 = ct*96+srow (max 735, safe); call1 clamped to 767 (pad rows,
    // never read: bf rows < 96). Swizzle slot uses intended row parity (= srow&7).
    const int br1 = (ct * 96 + 64 + srow > 767) ? 767 : (ct * 96 + 64 + srow);
    const _Float16* Bg0 = GT + (size_t)(ct * 96 + srow) * KPAD + schk * 8;
    const _Float16* Bg1 = GT + (size_t)br1 * KPAD + schk * 8;

#define SA0(s, kt) gload16(Ag + (kt) * 64,                    smem + A_OFF + (s) * 8192 + tid * 8)
#define SA1(s, kt) gload16(Ag + (size_t)64 * KPAD + (kt) * 64, smem + A_OFF + (s) * 8192 + 4096 + tid * 8)
#define SB0(s, kt) gload16(Bg0 + (kt) * 64,                   smem + B_OFF + (s) * 8192 + tid * 8)
#define SB1(s, kt) gload16(Bg1 + (kt) * 64,                   smem + B_OFF + (s) * 8192 + 4096 + tid * 8)

#define READ_A(s, kh, mf) (*(const f16x8*)(smem + A_OFF + (s) * 8192            \
    + (wm * 32 + (mf) * 16 + ln) * 64 + ((((kh) * 4 + quad) ^ (ln & 7)) * 8)))
#define READ_B(s, nf, kh) (*(const f16x8*)(smem + B_OFF + (s) * 8192            \
    + (wn * 48 + (nf) * 16 + ln) * 64 + ((((kh) * 4 + quad) ^ (ln & 7)) * 8)))
#define READ_X(bb, kh, t) (*(const f16x8*)(smem + X_OFF + (bb) * 2048           \
    + (t) * 64 + (kh) * 32 + quad * 8))

    // ---- prologue: X rows (4 b-planes, 2 calls), drain; tile0->buf0,
    //      tile1->buf1 (8 calls, ledger order), gate vmcnt(4) ----
    {
        const _Float16* xg = xb + (size_t)(b0 + (tid >> 8)) * KPAD + (tid & 255) * 8;
        gload16(xg,            smem + X_OFF + tid * 8);
        gload16(xg + 2 * KPAD, smem + X_OFF + 4096 + tid * 8);
    }
    __syncthreads();

    f32x4 acc[4][2][3];
#pragma unroll
    for (int bb = 0; bb < 4; ++bb)
#pragma unroll
        for (int i = 0; i < 2; ++i)
#pragma unroll
            for (int j = 0; j < 3; ++j)
                acc[bb][i][j] = (f32x4){0.f, 0.f, 0.f, 0.f};

    SA0(0, 0); SA1(0, 0); SB0(0, 0); SB1(0, 0);
    SA0(1, 1); SA1(1, 1); SB0(1, 1); SB1(1, 1);
    asm volatile("s_waitcnt vmcnt(4)" ::: "memory");   // tile0 landed
    BAR();

    int s = 0;                         // buffer holding tile t
    for (int t = 0; t < NT; ++t) {
        int sn = s + 2; if (sn >= 3) sn -= 3;          // buffer for tile t+2
        const bool st = (t + 2) < NT;
        f16x8 xq0[4], xq1[4], bf0[3], bf1[3], wf, af[4];

        // ===== P0: kh0, mf0 — reads wf+xq0[4]+bf0[3] | stage A0(t+2) =====
        wf = READ_A(s, 0, 0);
#pragma unroll
        for (int bb = 0; bb < 4; ++bb) xq0[bb] = READ_X(bb, 0, t);
#pragma unroll
        for (int nf = 0; nf < 3; ++nf) bf0[nf] = READ_B(s, nf, 0);
        if (st) SA0(sn, t + 2);
        BAR(); LGKM0();
        __builtin_amdgcn_s_setprio(1);
#pragma unroll
        for (int bb = 0; bb < 4; ++bb) af[bb] = wf * xq0[bb];
#pragma unroll
        for (int bb = 0; bb < 4; ++bb)
#pragma unroll
            for (int nf = 0; nf < 3; ++nf)
                acc[bb][0][nf] = __builtin_amdgcn_mfma_f32_16x16x32_f16(
                    af[bb], bf0[nf], acc[bb][0][nf], 0, 0, 0);
        __builtin_amdgcn_s_setprio(0);
        BAR();

        // ===== P1: kh0, mf1 — read wf | stage A1(t+2) =====
        wf = READ_A(s, 0, 1);
        if (st) SA1(sn, t + 2);
        BAR(); LGKM0();
        __builtin_amdgcn_s_setprio(1);
#pragma unroll
        for (int bb = 0; bb < 4; ++bb) af[bb] = wf * xq0[bb];
#pragma unroll
        for (int bb = 0; bb < 4; ++bb)
#pragma unroll
            for (int nf = 0; nf < 3; ++nf)
                acc[bb][1][nf] = __builtin_amdgcn_mfma_f32_16x16x32_f16(
                    af[bb], bf0[nf], acc[bb][1][nf], 0, 0, 0);
        __builtin_amdgcn_s_setprio(0);
        BAR();

        // ===== P2: kh1, mf0 — reads wf+xq1[4]+bf1[3] | stage B0(t+2) =====
        wf = READ_A(s, 1, 0);
#pragma unroll
        for (int bb = 0; bb < 4; ++bb) xq1[bb] = READ_X(bb, 1, t);
#pragma unroll
        for (int nf = 0; nf < 3; ++nf) bf1[nf] = READ_B(s, nf, 1);
        if (st) SB0(sn, t + 2);
        BAR(); LGKM0();
        __builtin_amdgcn_s_setprio(1);
#pragma unroll
        for (int bb = 0; bb < 4; ++bb) af[bb] = wf * xq1[bb];
#pragma unroll
        for (int bb = 0; bb < 4; ++bb)
#pragma unroll
            for (int nf = 0; nf < 3; ++nf)
                acc[bb][0][nf] = __builtin_amdgcn_mfma_f32_16x16x32_f16(
                    af[bb], bf1[nf], acc[bb][0][nf], 0, 0, 0);
        __builtin_amdgcn_s_setprio(0);
        BAR();

        // ===== P3: kh1, mf1 — read wf | stage B1(t+2) | GATE vmcnt(4) =====
        wf = READ_A(s, 1, 1);
        if (st) {
            SB1(sn, t + 2);
            asm volatile("s_waitcnt vmcnt(4)" ::: "memory");  // t+1 fully landed
        } else {
            asm volatile("s_waitcnt vmcnt(0)" ::: "memory");  // tail drain
        }
        BAR(); LGKM0();
        __builtin_amdgcn_s_setprio(1);
#pragma unroll
        for (int bb = 0; bb < 4; ++bb) af[bb] = wf * xq1[bb];
#pragma unroll
        for (int bb = 0; bb < 4; ++bb)
#pragma unroll
            for (int nf = 0; nf < 3; ++nf)
                acc[bb][1][nf] = __builtin_amdgcn_mfma_f32_16x16x32_f16(
                    af[bb], bf1[nf], acc[bb][1][nf], 0, 0, 0);
        __builtin_amdgcn_s_setprio(0);
        BAR();

        s = s + 1; if (s >= 3) s -= 3;
    }

    // ---- epilogue: C/D layout col=ln, row=quad*4+reg (m89/m91-verified) ----
#pragma unroll
    for (int bb = 0; bb < 4; ++bb) {
        const size_t obase = (size_t)(b0 + bb) * P_PATH * EMB;
#pragma unroll
        for (int mf = 0; mf < 2; ++mf) {
#pragma unroll
            for (int reg = 0; reg < 4; ++reg) {
                int p = ph * 128 + wm * 32 + mf * 16 + quad * 4 + reg;
                float bv = bias[p];
                size_t ro = obase + (size_t)p * EMB + ct * 96 + wn * 48 + ln;
#pragma unroll
                for (int nf = 0; nf < 3; ++nf)
                    out[ro + nf * 16] = acc[bb][mf][nf][reg] + bv;
            }
        }
    }
}

extern "C" void kernel_launch(void* const* d_in, const int* in_sizes, int n_in,
                              void* d_out, int out_size, void* d_ws, size_t ws_size,
                              hipStream_t stream) {
    // inputs (fp32): x(64x2000), weight(256x2000), bias(256), mask(unused), ge(2000x768)
    const float* x    = (const float*)d_in[0];
    const float* wgt  = (const float*)d_in[1];
    const float* bias = (const float*)d_in[2];
    const float* ge   = (const float*)d_in[4];
    float* out = (float*)d_out;

    char* ws = (char*)d_ws;
    unsigned short* xbuf = (unsigned short*)ws;                        // 262144 B
    unsigned short* Wbuf = (unsigned short*)(ws + 262144);             // 1048576 B
    unsigned short* GTb  = (unsigned short*)(ws + 262144 + 1048576);   // 3145728 B

    pack_xw_kernel<<<((BATCH + P_PATH) * 256) / 256, 256, 0, stream>>>(x, wgt, xbuf, Wbuf);
    transpose_ge_kernel<<<64 * 12, 256, 0, stream>>>(ge, GTb);
    gemm_kernel<<<dim3(256), dim3(512), 0, stream>>>(
        (const _Float16*)xbuf, (const _Float16*)Wbuf, (const _Float16*)GTb, bias, out);
}

// Round 10
// 121.338 us; speedup vs baseline: 1.1118x; 1.1118x over previous
//
#include <hip/hip_runtime.h>
#include <stdint.h>
#include <stddef.h>

// out[b, p*768+e] = sum_d x[b,d]*W[p,d]*GE[d,e] + bias[p]
// == per-b GEMM: OUT_b(256x768) = (diag(x_b) W)(256x2048) @ GT^T + bias
//
// R15 == R14 resubmitted (R14's bench died on container acquisition, no
// data). R14 rationale: R13 (m201 4-phase port) regressed to 64.6us/29% -
// 8 barriers/tile cost ~1100 cyc/tile, confirming (with R10) that phase
// discipline loses to R12's open region at this geometry. R12 structure
// kept (best: 50.3us, MfmaUtil 40%) + BK=128:
// - barriers 32 -> 16; staging calls/tile 8 -> 7
// - 4 kh-sections per open region -> more room for compiler to pipeline
//   next-kh ds_reads under current-kh MFMAs (m97-verified mechanism)
// - LDS exactly 128KB (A 64 + B 48 + X 16), 1 block/CU, 8 waves, 2/SIMD
// - swizzle generalized to 16-chunk rows: read chunk (kh*4+quad)^(ln&7),
//   stage src chunk (tid&15)^(row&7); XOR on low 3 bits, bijective per
//   half, same conflict-free bank walk as the R5/R12-verified pattern.
//
// Workspace: xb 64x2048 f16 (262144 B) | Wb 256x2048 f16 (1048576 B) |
// GT 768x2048 f16 (3145728 B) = 4,456,448 B total.

#define F_GENES 2000
#define KPAD    2048
#define P_PATH  256
#define EMB     768
#define BATCH   64
#define NT      16        // K tiles of BK=128

typedef _Float16 f16x8 __attribute__((ext_vector_type(8)));
typedef float    f32x4 __attribute__((ext_vector_type(4)));

__device__ __forceinline__ unsigned short f2h(float f) {
    union { _Float16 h; unsigned short s; } v; v.h = (_Float16)f; return v.s;
}

__device__ __forceinline__ void gload16(const void* g, void* l) {
    __builtin_amdgcn_global_load_lds((const __attribute__((address_space(1))) void*)g,
                                     (__attribute__((address_space(3))) void*)l,
                                     16, 0, 0);
}

// K1: pack x (64 rows) + W (256 rows) fp32 -> fp16, K-padded to 2048 w/ zeros.
__global__ void pack_xw_kernel(const float* __restrict__ x,
                               const float* __restrict__ w,
                               unsigned short* __restrict__ xb,
                               unsigned short* __restrict__ wb) {
    int gid = blockIdx.x * 256 + threadIdx.x;
    int row = gid >> 8;
    int s   = gid & 255;
    int d0  = s * 8;
    const float* src;
    unsigned short* dst;
    if (row < BATCH) { src = x + (size_t)row * F_GENES;           dst = xb + (size_t)row * KPAD; }
    else             { src = w + (size_t)(row - BATCH) * F_GENES; dst = wb + (size_t)(row - BATCH) * KPAD; }
    uint4 ov = make_uint4(0u, 0u, 0u, 0u);
    if (s < 250) {
        float4 v0 = *(const float4*)(src + d0);
        float4 v1 = *(const float4*)(src + d0 + 4);
        unsigned short* os = (unsigned short*)&ov;
        os[0] = f2h(v0.x); os[1] = f2h(v0.y); os[2] = f2h(v0.z); os[3] = f2h(v0.w);
        os[4] = f2h(v1.x); os[5] = f2h(v1.y); os[6] = f2h(v1.z); os[7] = f2h(v1.w);
    }
    *(uint4*)(dst + d0) = ov;
}

// K2: GT[n,k] = f16(GE[k,n]), k-padded to 2048.
__global__ void transpose_ge_kernel(const float* __restrict__ ge,
                                    unsigned short* __restrict__ GT) {
    __shared__ unsigned short tile[64][40];
    int kt = blockIdx.x & 63;
    int nt = blockIdx.x >> 6;
    int k0 = kt * 32, n0 = nt * 64;
    int t  = threadIdx.x;
    int kr = t >> 4;
    int nc = (t & 15) * 4;
#pragma unroll
    for (int p = 0; p < 2; ++p) {
        int k = k0 + p * 16 + kr;
        float4 v = make_float4(0.f, 0.f, 0.f, 0.f);
        if (k < F_GENES) v = *(const float4*)(ge + (size_t)k * EMB + n0 + nc);
        int kk = p * 16 + kr;
        tile[nc + 0][kk] = f2h(v.x);
        tile[nc + 1][kk] = f2h(v.y);
        tile[nc + 2][kk] = f2h(v.z);
        tile[nc + 3][kk] = f2h(v.w);
    }
    __syncthreads();
    int n  = t >> 2;
    int kc = (t & 3) * 8;
    uint4 o;
    unsigned short* os = (unsigned short*)&o;
#pragma unroll
    for (int j = 0; j < 8; ++j) os[j] = tile[n][kc + j];
    *(uint4*)(GT + (size_t)(n0 + n) * KPAD + k0 + kc) = o;
}

// ---- GEMM: 4-batch-shared 128x96 tile, BK=128, 8 waves, depth-2 prefetch ----
// LDS (f16 units): A [2 dbuf][128 row][128 k] @0      (32768 f16, 64 KB)
//                  B [2 dbuf][ 96 row][128 k] @32768  (24576 f16, 48 KB)
//                  X [4 b][2048 k]            @57344  ( 8192 f16, 16 KB)
#define A_OFF 0
#define B_OFF 32768
#define X_OFF 57344

__global__ __launch_bounds__(512, 2)
void gemm_kernel(const _Float16* __restrict__ xb, const _Float16* __restrict__ Wb,
                 const _Float16* __restrict__ GT, const float* __restrict__ bias,
                 float* __restrict__ out) {
    __shared__ __align__(16) _Float16 smem[65536];   // 128 KB

    const int tid  = threadIdx.x;
    const int wv   = tid >> 6;        // wave 0..7
    const int l    = tid & 63;
    const int quad = l >> 4;
    const int ln   = l & 15;
    const int wm   = wv >> 1;         // 0..3 (32 p-rows each)
    const int wn   = wv & 1;          // 0..1 (48 cols each)

    const int ct = blockIdx.x & 7;          // 768 / 96
    const int ph = (blockIdx.x >> 3) & 1;   // pathway half (128 rows of W)
    const int bq = blockIdx.x >> 4;         // batch quad 0..15
    const int b0 = 4 * bq;

    // staging maps: rows of 128 f16 (256B) = 16 threads/row (16B chunks).
    // row = call*32 + (tid>>4), chunk slot = tid&15,
    // source chunk = slot ^ (row&7) = slot ^ ((tid>>4)&7); LDS dest linear tid*8.
    const int srow = tid >> 4;        // 0..31
    const int schk = (tid & 15) ^ (srow & 7);
    const _Float16* Ag = Wb + (size_t)(ph * 128 + srow) * KPAD + schk * 8;
    const _Float16* Bg = GT + (size_t)(ct * 96 + srow) * KPAD + schk * 8;

    // stage K-tile kt (128 wide) into dbuf d: A 4 calls + B 3 calls (8 KB each)
#define STAGE_TILE(d, kt) do {                                                  \
    _Pragma("unroll")                                                           \
    for (int c = 0; c < 4; ++c)                                                 \
        gload16(Ag + (size_t)c * 32 * KPAD + (kt) * 128,                        \
                smem + A_OFF + (d) * 16384 + c * 4096 + tid * 8);               \
    _Pragma("unroll")                                                           \
    for (int c = 0; c < 3; ++c)                                                 \
        gload16(Bg + (size_t)c * 32 * KPAD + (kt) * 128,                        \
                smem + B_OFF + (d) * 12288 + c * 4096 + tid * 8);               \
} while (0)

    // ---- prologue: X (4 rows, 2 calls) + tile0; one full drain ----
    {
        const _Float16* xg = xb + (size_t)(b0 + (tid >> 8)) * KPAD + (tid & 255) * 8;
        gload16(xg,            smem + X_OFF + tid * 8);
        gload16(xg + 2 * KPAD, smem + X_OFF + 4096 + tid * 8);
    }
    STAGE_TILE(0, 0);
    __syncthreads();

    f32x4 acc[4][2][3];
#pragma unroll
    for (int bb = 0; bb < 4; ++bb)
#pragma unroll
        for (int i = 0; i < 2; ++i)
#pragma unroll
            for (int j = 0; j < 3; ++j)
                acc[bb][i][j] = (f32x4){0.f, 0.f, 0.f, 0.f};

    const _Float16* As = smem + A_OFF;
    const _Float16* Bs = smem + B_OFF;
    const _Float16* Xs = smem + X_OFF;

    for (int t = 0; t < NT; ++t) {
        const int d = t & 1;
        // depth-2: issue next tile's staging first; drained by the barrier
        // at the END of this tile (~1 tile-body later - latency long gone)
        if (t + 1 < NT) STAGE_TILE(d ^ 1, t + 1);

        // compute tile t: 4 kh-sections, open region (compiler pipelines)
#pragma unroll
        for (int kh = 0; kh < 4; ++kh) {
            const int swz = ((kh * 4 + quad) ^ (ln & 7)) * 8;
            f16x8 bf[3];
#pragma unroll
            for (int nf = 0; nf < 3; ++nf)
                bf[nf] = *(const f16x8*)(Bs + d * 12288
                              + (wn * 48 + nf * 16 + ln) * 128 + swz);
            f16x8 xq[4];
#pragma unroll
            for (int bb = 0; bb < 4; ++bb)   // same-address broadcast per quad
                xq[bb] = *(const f16x8*)(Xs + bb * 2048 + t * 128 + kh * 32 + quad * 8);
#pragma unroll
            for (int mf = 0; mf < 2; ++mf) {
                f16x8 wf = *(const f16x8*)(As + d * 16384
                              + (wm * 32 + mf * 16 + ln) * 128 + swz);
#pragma unroll
                for (int bb = 0; bb < 4; ++bb) {
                    f16x8 af = wf * xq[bb];          // v_pk_mul_f16 x4
#pragma unroll
                    for (int nf = 0; nf < 3; ++nf)
                        acc[bb][mf][nf] = __builtin_amdgcn_mfma_f32_16x16x32_f16(
                            af, bf[nf], acc[bb][mf][nf], 0, 0, 0);
                }
            }
        }

        // single barrier/tile: publishes dbuf free + drains t+1's staging
        __syncthreads();
    }

    // ---- epilogue: C/D layout col=ln, row=quad*4+reg (m89/m91-verified) ----
#pragma unroll
    for (int bb = 0; bb < 4; ++bb) {
        const size_t obase = (size_t)(b0 + bb) * P_PATH * EMB;
#pragma unroll
        for (int mf = 0; mf < 2; ++mf) {
#pragma unroll
            for (int reg = 0; reg < 4; ++reg) {
                int p = ph * 128 + wm * 32 + mf * 16 + quad * 4 + reg;
                float bv = bias[p];
                size_t ro = obase + (size_t)p * EMB + ct * 96 + wn * 48 + ln;
#pragma unroll
                for (int nf = 0; nf < 3; ++nf)
                    out[ro + nf * 16] = acc[bb][mf][nf][reg] + bv;
            }
        }
    }
}

extern "C" void kernel_launch(void* const* d_in, const int* in_sizes, int n_in,
                              void* d_out, int out_size, void* d_ws, size_t ws_size,
                              hipStream_t stream) {
    // inputs (fp32): x(64x2000), weight(256x2000), bias(256), mask(unused), ge(2000x768)
    const float* x    = (const float*)d_in[0];
    const float* wgt  = (const float*)d_in[1];
    const float* bias = (const float*)d_in[2];
    const float* ge   = (const float*)d_in[4];
    float* out = (float*)d_out;

    char* ws = (char*)d_ws;
    unsigned short* xbuf = (unsigned short*)ws;                        // 262144 B
    unsigned short* Wbuf = (unsigned short*)(ws + 262144);             // 1048576 B
    unsigned short* GTb  = (unsigned short*)(ws + 262144 + 1048576);   // 3145728 B

    pack_xw_kernel<<<((BATCH + P_PATH) * 256) / 256, 256, 0, stream>>>(x, wgt, xbuf, Wbuf);
    transpose_ge_kernel<<<64 * 12, 256, 0, stream>>>(ge, GTb);
    gemm_kernel<<<dim3(256), dim3(512), 0, stream>>>(
        (const _Float16*)xbuf, (const _Float16*)Wbuf, (const _Float16*)GTb, bias, out);
}

// Round 11
// 120.047 us; speedup vs baseline: 1.1237x; 1.0108x over previous
//
#include <hip/hip_runtime.h>
#include <stdint.h>
#include <stddef.h>

// out[b, p*768+e] = sum_d x[b,d]*W[p,d]*GE[d,e] + bias[p]
// == per-b GEMM: OUT_b(256x768) = (diag(x_b) W)(256x2048) @ GT^T + bias
//
// R16 vs R15: R15 (BK=128, best 49.5us) had 2.62M bank-conflict cycles =
// exactly 4/swizzled-read: 256B rows are bank-degenerate (row*256 = 0 mod
// 128-B bank cycle) so the 4-bit chunk XOR on 3 bits leaves conflicts.
// Fix: keep BK=128's outer loop (16 barriers, 7 stage calls/tile) but
// store each K-tile as TWO kh-planes of 64 f16 = 128-B rows - the exact
// layout+swizzle family R12 measured at 0 conflicts. A[2][2][128][64],
// B[2][2][96][64], X[4][2048]; LDS still exactly 128 KB, 1 blk/CU, 8
// waves, 2/SIMD. Stage: 8 thr/row, src chunk (tid&7)^(srow&7), linear
// dest; B per plane = 1 full + 1 half (tid<256) call, wave-uniform.
// Reads: swz = ((khq*4+quad)^(ln&7))*8 per plane (khq = kh&1).
// Depth-2 prefetch + one __syncthreads/tile + open region: unchanged.
//
// Workspace: xb 64x2048 f16 (262144 B) | Wb 256x2048 f16 (1048576 B) |
// GT 768x2048 f16 (3145728 B) = 4,456,448 B total.

#define F_GENES 2000
#define KPAD    2048
#define P_PATH  256
#define EMB     768
#define BATCH   64
#define NT      16        // K tiles of BK=128

typedef _Float16 f16x8 __attribute__((ext_vector_type(8)));
typedef float    f32x4 __attribute__((ext_vector_type(4)));

__device__ __forceinline__ unsigned short f2h(float f) {
    union { _Float16 h; unsigned short s; } v; v.h = (_Float16)f; return v.s;
}

__device__ __forceinline__ void gload16(const void* g, void* l) {
    __builtin_amdgcn_global_load_lds((const __attribute__((address_space(1))) void*)g,
                                     (__attribute__((address_space(3))) void*)l,
                                     16, 0, 0);
}

// K1: pack x (64 rows) + W (256 rows) fp32 -> fp16, K-padded to 2048 w/ zeros.
__global__ void pack_xw_kernel(const float* __restrict__ x,
                               const float* __restrict__ w,
                               unsigned short* __restrict__ xb,
                               unsigned short* __restrict__ wb) {
    int gid = blockIdx.x * 256 + threadIdx.x;
    int row = gid >> 8;
    int s   = gid & 255;
    int d0  = s * 8;
    const float* src;
    unsigned short* dst;
    if (row < BATCH) { src = x + (size_t)row * F_GENES;           dst = xb + (size_t)row * KPAD; }
    else             { src = w + (size_t)(row - BATCH) * F_GENES; dst = wb + (size_t)(row - BATCH) * KPAD; }
    uint4 ov = make_uint4(0u, 0u, 0u, 0u);
    if (s < 250) {
        float4 v0 = *(const float4*)(src + d0);
        float4 v1 = *(const float4*)(src + d0 + 4);
        unsigned short* os = (unsigned short*)&ov;
        os[0] = f2h(v0.x); os[1] = f2h(v0.y); os[2] = f2h(v0.z); os[3] = f2h(v0.w);
        os[4] = f2h(v1.x); os[5] = f2h(v1.y); os[6] = f2h(v1.z); os[7] = f2h(v1.w);
    }
    *(uint4*)(dst + d0) = ov;
}

// K2: GT[n,k] = f16(GE[k,n]), k-padded to 2048.
__global__ void transpose_ge_kernel(const float* __restrict__ ge,
                                    unsigned short* __restrict__ GT) {
    __shared__ unsigned short tile[64][40];
    int kt = blockIdx.x & 63;
    int nt = blockIdx.x >> 6;
    int k0 = kt * 32, n0 = nt * 64;
    int t  = threadIdx.x;
    int kr = t >> 4;
    int nc = (t & 15) * 4;
#pragma unroll
    for (int p = 0; p < 2; ++p) {
        int k = k0 + p * 16 + kr;
        float4 v = make_float4(0.f, 0.f, 0.f, 0.f);
        if (k < F_GENES) v = *(const float4*)(ge + (size_t)k * EMB + n0 + nc);
        int kk = p * 16 + kr;
        tile[nc + 0][kk] = f2h(v.x);
        tile[nc + 1][kk] = f2h(v.y);
        tile[nc + 2][kk] = f2h(v.z);
        tile[nc + 3][kk] = f2h(v.w);
    }
    __syncthreads();
    int n  = t >> 2;
    int kc = (t & 3) * 8;
    uint4 o;
    unsigned short* os = (unsigned short*)&o;
#pragma unroll
    for (int j = 0; j < 8; ++j) os[j] = tile[n][kc + j];
    *(uint4*)(GT + (size_t)(n0 + n) * KPAD + k0 + kc) = o;
}

// ---- GEMM: 4-batch-shared 128x96, BK=128 as 2x 128-B-row kh-planes ----
// LDS (f16 units): A [2 dbuf][2 pl][128 row][64] @0      (32768 f16, 64 KB)
//                  B [2 dbuf][2 pl][ 96 row][64] @32768  (24576 f16, 48 KB)
//                  X [4 b][2048 k]               @57344  ( 8192 f16, 16 KB)
#define A_OFF 0
#define B_OFF 32768
#define X_OFF 57344

__global__ __launch_bounds__(512, 2)
void gemm_kernel(const _Float16* __restrict__ xb, const _Float16* __restrict__ Wb,
                 const _Float16* __restrict__ GT, const float* __restrict__ bias,
                 float* __restrict__ out) {
    __shared__ __align__(16) _Float16 smem[65536];   // 128 KB

    const int tid  = threadIdx.x;
    const int wv   = tid >> 6;        // wave 0..7
    const int l    = tid & 63;
    const int quad = l >> 4;
    const int ln   = l & 15;
    const int wm   = wv >> 1;         // 0..3 (32 p-rows each)
    const int wn   = wv & 1;          // 0..1 (48 cols each)

    const int ct = blockIdx.x & 7;          // 768 / 96
    const int ph = (blockIdx.x >> 3) & 1;   // pathway half (128 rows of W)
    const int bq = blockIdx.x >> 4;         // batch quad 0..15
    const int b0 = 4 * bq;

    // staging maps (128-B rows): 8 threads/row, row = call-base + (tid>>3),
    // chunk slot = tid&7, src chunk = slot ^ (srow&7); LDS dest linear tid*8.
    const int srow = tid >> 3;        // 0..63
    const int schk = (tid & 7) ^ (srow & 7);
    const _Float16* Ag = Wb + (size_t)(ph * 128 + srow) * KPAD + schk * 8;
    const _Float16* Bg = GT + (size_t)(ct * 96 + srow) * KPAD + schk * 8;
    // B half-call (rows 64..95): only tid<256 (srow2 = tid>>3 in 0..31)
    const _Float16* Bg2 = GT + (size_t)(ct * 96 + 64 + srow) * KPAD + schk * 8;

    // stage K-tile kt (BK=128 = 2 planes of 64 f16) into dbuf d: 7 calls
#define STAGE_TILE(d, kt) do {                                                  \
    _Pragma("unroll")                                                           \
    for (int pl = 0; pl < 2; ++pl) {                                            \
        _Pragma("unroll")                                                       \
        for (int c = 0; c < 2; ++c)                                             \
            gload16(Ag + (size_t)c * 64 * KPAD + (kt) * 128 + pl * 64,          \
                    smem + A_OFF + (d) * 16384 + pl * 8192 + c * 4096 + tid * 8); \
        gload16(Bg + (kt) * 128 + pl * 64,                                      \
                smem + B_OFF + (d) * 12288 + pl * 6144 + tid * 8);              \
        if (tid < 256)                                                          \
            gload16(Bg2 + (kt) * 128 + pl * 64,                                 \
                    smem + B_OFF + (d) * 12288 + pl * 6144 + 4096 + tid * 8);   \
    }                                                                           \
} while (0)

    // ---- prologue: X (4 rows, 2 calls) + tile0; one full drain ----
    {
        const _Float16* xg = xb + (size_t)(b0 + (tid >> 8)) * KPAD + (tid & 255) * 8;
        gload16(xg,            smem + X_OFF + tid * 8);
        gload16(xg + 2 * KPAD, smem + X_OFF + 4096 + tid * 8);
    }
    STAGE_TILE(0, 0);
    __syncthreads();

    f32x4 acc[4][2][3];
#pragma unroll
    for (int bb = 0; bb < 4; ++bb)
#pragma unroll
        for (int i = 0; i < 2; ++i)
#pragma unroll
            for (int j = 0; j < 3; ++j)
                acc[bb][i][j] = (f32x4){0.f, 0.f, 0.f, 0.f};

    const _Float16* As = smem + A_OFF;
    const _Float16* Bs = smem + B_OFF;
    const _Float16* Xs = smem + X_OFF;

    for (int t = 0; t < NT; ++t) {
        const int d = t & 1;
        // depth-2: issue next tile's staging first; drained by the barrier
        // at the END of this tile (~1 tile-body later - latency long gone)
        if (t + 1 < NT) STAGE_TILE(d ^ 1, t + 1);

        // compute tile t: 4 kh-sections (plane = kh>>1, khq = kh&1)
#pragma unroll
        for (int kh = 0; kh < 4; ++kh) {
            const int pl  = kh >> 1;
            const int khq = kh & 1;
            const int swz = ((khq * 4 + quad) ^ (ln & 7)) * 8;   // R12-proven
            f16x8 bf[3];
#pragma unroll
            for (int nf = 0; nf < 3; ++nf)
                bf[nf] = *(const f16x8*)(Bs + d * 12288 + pl * 6144
                              + (wn * 48 + nf * 16 + ln) * 64 + swz);
            f16x8 xq[4];
#pragma unroll
            for (int bb = 0; bb < 4; ++bb)   // same-address broadcast per quad
                xq[bb] = *(const f16x8*)(Xs + bb * 2048 + t * 128 + kh * 32 + quad * 8);
#pragma unroll
            for (int mf = 0; mf < 2; ++mf) {
                f16x8 wf = *(const f16x8*)(As + d * 16384 + pl * 8192
                              + (wm * 32 + mf * 16 + ln) * 64 + swz);
#pragma unroll
                for (int bb = 0; bb < 4; ++bb) {
                    f16x8 af = wf * xq[bb];          // v_pk_mul_f16 x4
#pragma unroll
                    for (int nf = 0; nf < 3; ++nf)
                        acc[bb][mf][nf] = __builtin_amdgcn_mfma_f32_16x16x32_f16(
                            af, bf[nf], acc[bb][mf][nf], 0, 0, 0);
                }
            }
        }

        // single barrier/tile: publishes dbuf free + drains t+1's staging
        __syncthreads();
    }

    // ---- epilogue: C/D layout col=ln, row=quad*4+reg (m89/m91-verified) ----
#pragma unroll
    for (int bb = 0; bb < 4; ++bb) {
        const size_t obase = (size_t)(b0 + bb) * P_PATH * EMB;
#pragma unroll
        for (int mf = 0; mf < 2; ++mf) {
#pragma unroll
            for (int reg = 0; reg < 4; ++reg) {
                int p = ph * 128 + wm * 32 + mf * 16 + quad * 4 + reg;
                float bv = bias[p];
                size_t ro = obase + (size_t)p * EMB + ct * 96 + wn * 48 + ln;
#pragma unroll
                for (int nf = 0; nf < 3; ++nf)
                    out[ro + nf * 16] = acc[bb][mf][nf][reg] + bv;
            }
        }
    }
}

extern "C" void kernel_launch(void* const* d_in, const int* in_sizes, int n_in,
                              void* d_out, int out_size, void* d_ws, size_t ws_size,
                              hipStream_t stream) {
    // inputs (fp32): x(64x2000), weight(256x2000), bias(256), mask(unused), ge(2000x768)
    const float* x    = (const float*)d_in[0];
    const float* wgt  = (const float*)d_in[1];
    const float* bias = (const float*)d_in[2];
    const float* ge   = (const float*)d_in[4];
    float* out = (float*)d_out;

    char* ws = (char*)d_ws;
    unsigned short* xbuf = (unsigned short*)ws;                        // 262144 B
    unsigned short* Wbuf = (unsigned short*)(ws + 262144);             // 1048576 B
    unsigned short* GTb  = (unsigned short*)(ws + 262144 + 1048576);   // 3145728 B

    pack_xw_kernel<<<((BATCH + P_PATH) * 256) / 256, 256, 0, stream>>>(x, wgt, xbuf, Wbuf);
    transpose_ge_kernel<<<64 * 12, 256, 0, stream>>>(ge, GTb);
    gemm_kernel<<<dim3(256), dim3(512), 0, stream>>>(
        (const _Float16*)xbuf, (const _Float16*)Wbuf, (const _Float16*)GTb, bias, out);
}